// Round 22
// baseline (135.359 us; speedup 1.0000x reference)
//
#include <hip/hip_runtime.h>
#include <hip/hip_bf16.h>

// AttentionBlock: groupnorm -> qkv conv1x1 -> MHA (8 heads, hd=64) -> proj -> residual
// B=16, C=512, H=W=32 (HW=1024). All GEMM-shaped work in bf16 MFMA, fp32 accum.

typedef __bf16 bf16;
typedef __attribute__((ext_vector_type(8))) __bf16 bf16x8;
typedef __attribute__((ext_vector_type(4))) float f32x4;
typedef __attribute__((ext_vector_type(16))) float f32x16;
typedef __attribute__((ext_vector_type(4))) unsigned int u32x4;

#define SCALE_Q 0.18033688f  // 0.125 * log2(e), folded into q at gemm epilogue

__device__ __forceinline__ bf16x8 ld8(const bf16* p) {
    return *reinterpret_cast<const bf16x8*>(p);
}

__device__ __forceinline__ void gl_lds16(const void* g, void* l) {
    __builtin_amdgcn_global_load_lds(
        (const __attribute__((address_space(1))) void*)g,
        (__attribute__((address_space(3))) void*)l, 16, 0, 0);
}

// ---------------- one-pass groupnorm + weight cvt, 128 blocks ----------------
__global__ __launch_bounds__(256) void gn_cvt_onepass(const float* __restrict__ x,
                                                      const float* __restrict__ gamma,
                                                      const float* __restrict__ beta,
                                                      bf16* __restrict__ hnT,
                                                      const float* __restrict__ qkv_w,
                                                      const float* __restrict__ proj_w,
                                                      bf16* __restrict__ wdst,
                                                      bf16* __restrict__ xbf) {
    extern __shared__ char dsm[];            // 131072B cache + 64B reduce scratch
    bf16* xc = (bf16*)dsm;                   // [64 c][128 chunks][8 p] swizzled
    float* red = (float*)(dsm + 131072);
    int bg = blockIdx.x;
    int b = bg >> 3, g = bg & 7;
    const float* base = x + (size_t)bg * 65536;
    int t = threadIdx.x, wave = t >> 6, lane = t & 63;

    // ---- weight cvt chunk: 8192 elems/block (blocks 0..95 qkv, 96..127 proj) ----
    {
        const float* src = (bg < 96) ? qkv_w + bg * 8192 : proj_w + (bg - 96) * 8192;
        bf16* dst = wdst + (size_t)bg * 8192;
        #pragma unroll
        for (int k = 0; k < 8; k++) {
            int i = k * 1024 + t * 4;
            float4 f = *reinterpret_cast<const float4*>(src + i);
            dst[i + 0] = (bf16)f.x;
            dst[i + 1] = (bf16)f.y;
            dst[i + 2] = (bf16)f.z;
            dst[i + 3] = (bf16)f.w;
        }
    }

    // ---- pass 1: stream x, accumulate stats, cache bf16 in LDS ----
    float s = 0.f, sq = 0.f;
    int pc = t >> 1, half = t & 1;
    {
        for (int k = 0; k < 64; k++) {
            float4 f = *reinterpret_cast<const float4*>(base + (size_t)k * 1024 + t * 4);
            s += (f.x + f.y) + (f.z + f.w);
            sq += (f.x * f.x + f.y * f.y) + (f.z * f.z + f.w * f.w);
            unsigned pk0, pk1;
            asm("v_cvt_pk_bf16_f32 %0, %1, %2" : "=v"(pk0) : "v"(f.x), "v"(f.y));
            asm("v_cvt_pk_bf16_f32 %0, %1, %2" : "=v"(pk1) : "v"(f.z), "v"(f.w));
            char* dst = (char*)xc + k * 2048 + ((pc ^ (k & 7)) * 16) + half * 8;
            *reinterpret_cast<uint2*>(dst) = make_uint2(pk0, pk1);
        }
    }
    #pragma unroll
    for (int off = 32; off > 0; off >>= 1) {
        s += __shfl_down(s, off);
        sq += __shfl_down(sq, off);
    }
    if (lane == 0) { red[wave] = s; red[4 + wave] = sq; }
    __syncthreads();
    if (t == 0) {
        float S = (red[0] + red[1]) + (red[2] + red[3]);
        float Q = (red[4] + red[5]) + (red[6] + red[7]);
        float mean = S * (1.f / 65536.f);
        float var = Q * (1.f / 65536.f) - mean * mean;
        red[8] = mean;
        red[9] = rsqrtf(var + 1e-5f);
    }
    __syncthreads();
    float mean = red[8], rstd = red[9];

    // ---- xbf dump: read back own LDS lines, fire-and-forget stores ----
    if (xbf) {
        bf16* xo = xbf + (size_t)bg * 65536;
        for (int k = 0; k < 64; k++) {
            const char* src = (const char*)xc + k * 2048 + ((pc ^ (k & 7)) * 16) + half * 8;
            uint2 v = *reinterpret_cast<const uint2*>(src);
            *reinterpret_cast<uint2*>(xo + (size_t)k * 1024 + t * 4) = v;
        }
    }

    // ---- pass 2: normalize + transpose from LDS cache ----
    int cl = t & 63, quad = t >> 6;
    float ga = gamma[g * 64 + cl] * rstd;
    float be = beta[g * 64 + cl] - mean * ga;
    const char* rowbase = (const char*)xc + cl * 2048;
    int rx = cl & 7;
    bf16* obase = hnT + (size_t)b * 1024 * 512 + g * 64 + cl;
    #pragma unroll 4
    for (int j = 0; j < 32; j++) {
        int pcj = quad + 4 * j;                      // chunk 0..127
        bf16x8 v = *reinterpret_cast<const bf16x8*>(rowbase + ((pcj ^ rx) * 16));
        bf16* ob = obase + (size_t)(pcj * 8) * 512;
        #pragma unroll
        for (int e = 0; e < 8; e++)
            ob[(size_t)e * 512] = (bf16)((float)v[e] * ga + be);
    }
}

// ---------------- staged NT-GEMM core (m97 structure + counted-vmcnt loop) ----------------
__device__ __forceinline__ void gemm_stage(const bf16* __restrict__ A,
                                           const bf16* __restrict__ B,
                                           char* smem, int buf,
                                           int m_blk, int n_blk, int k0,
                                           int wave, int lane) {
    char* Al = smem + buf * 32768;
    char* Bl = Al + 16384;
    #pragma unroll
    for (int i = 0; i < 4; i++) {
        int seg = i * 4 + wave;              // 16 segs of 1KB per 16KB tile
        int r = seg * 8 + (lane >> 3);       // tile row this lane fills
        int cg = (lane & 7) ^ (r & 7);       // pre-swizzled source chunk
        gl_lds16((const char*)(A + (size_t)(m_blk + r) * 512 + k0) + cg * 16,
                 Al + seg * 1024);
        gl_lds16((const char*)(B + (size_t)(n_blk + r) * 512 + k0) + cg * 16,
                 Bl + seg * 1024);
    }
}

__device__ __forceinline__ void gemm_compute(const char* smem, int buf,
                                             int wave, int lane,
                                             f32x4 (&acc)[4][4]) {
    const char* Al = smem + buf * 32768;
    const char* Bl = Al + 16384;
    int l15 = lane & 15, hi = lane >> 4;
    int mb = (wave >> 1) * 64, nb = (wave & 1) * 64;
    #pragma unroll
    for (int kc = 0; kc < 2; kc++) {
        int ck = kc * 4 + hi;                // 16B chunk of the 64-wide k-slab
        bf16x8 a[4], b[4];
        #pragma unroll
        for (int mf = 0; mf < 4; mf++) {
            int row = mb + mf * 16 + l15;
            a[mf] = *reinterpret_cast<const bf16x8*>(Al + row * 128 + (ck ^ (row & 7)) * 16);
        }
        #pragma unroll
        for (int nf = 0; nf < 4; nf++) {
            int row = nb + nf * 16 + l15;
            b[nf] = *reinterpret_cast<const bf16x8*>(Bl + row * 128 + (ck ^ (row & 7)) * 16);
        }
        #pragma unroll
        for (int mf = 0; mf < 4; mf++)
            #pragma unroll
            for (int nf = 0; nf < 4; nf++)
                acc[mf][nf] = __builtin_amdgcn_mfma_f32_16x16x32_bf16(
                    a[mf], b[nf], acc[mf][nf], 0, 0, 0);
    }
}

// Counted-vmcnt double-barrier K-loop (r21, verified): each wave waits only its
// own previous stage (8 loads) so next-tile DMA stays in flight across barriers.
#define GEMM_LDS_LOOP(A_, B_, SMEM_)                                           \
    f32x4 acc[4][4] = {};                                                      \
    {                                                                          \
        gemm_stage(A_, B_, SMEM_, 0, m_blk, n_blk, 0, wave, lane);             \
        for (int ks = 0; ks < 8; ks++) {                                       \
            asm volatile("" ::: "memory");                                     \
            __builtin_amdgcn_s_barrier();                                      \
            if (ks < 7) {                                                      \
                gemm_stage(A_, B_, SMEM_, (ks + 1) & 1, m_blk, n_blk,          \
                           (ks + 1) * 64, wave, lane);                         \
                asm volatile("s_waitcnt vmcnt(8)" ::: "memory");               \
            } else {                                                           \
                asm volatile("s_waitcnt vmcnt(0)" ::: "memory");               \
            }                                                                  \
            __builtin_amdgcn_s_barrier();                                      \
            asm volatile("" ::: "memory");                                     \
            gemm_compute(SMEM_, ks & 1, wave, lane, acc);                      \
        }                                                                      \
    }

// Fused QKV GEMM, one launch. y<8: qk path; y>=8: v path.
__global__ __launch_bounds__(256, 2) void gemm_qkv(const bf16* __restrict__ hnT,
                                                   const bf16* __restrict__ wqkv,
                                                   const float* __restrict__ qkv_b,
                                                   bf16* __restrict__ qk_t,
                                                   bf16* __restrict__ vbuf) {
    __shared__ char smem[65536];
    int b = blockIdx.z;
    int wave = threadIdx.x >> 6, lane = threadIdx.x & 63;
    int l15 = lane & 15;
    int y = blockIdx.y;
    if (y < 8) {
        int m_blk = blockIdx.x * 128;        // p
        int n_blk = y * 128;                 // o
        const bf16* A = hnT + (size_t)b * 1024 * 512;
        GEMM_LDS_LOOP(A, wqkv, smem)
        bf16* out = qk_t + (size_t)b * 1024 * 1024;
        int col0 = n_blk + (wave & 1) * 64 + l15;
        int row0 = m_blk + (wave >> 1) * 64 + (lane >> 4) * 4;
        #pragma unroll
        for (int nf = 0; nf < 4; nf++) {
            int col = col0 + nf * 16;
            float bias = qkv_b[col];
            float scl = (col < 512) ? SCALE_Q : 1.0f;
            #pragma unroll
            for (int mf = 0; mf < 4; mf++)
                #pragma unroll
                for (int r = 0; r < 4; r++)
                    out[(size_t)(row0 + mf * 16 + r) * 1024 + col] =
                        (bf16)((acc[mf][nf][r] + bias) * scl);
        }
    } else {
        int m_blk = (y - 8) * 128;           // o
        int n_blk = blockIdx.x * 128;        // p
        const bf16* A = wqkv + (size_t)1024 * 512;   // wv
        const bf16* Bm = hnT + (size_t)b * 1024 * 512;
        GEMM_LDS_LOOP(A, Bm, smem)
        bf16* out = vbuf + (size_t)b * 512 * 1024;
        int col0 = n_blk + (wave & 1) * 64 + l15;
        int row0 = m_blk + (wave >> 1) * 64 + (lane >> 4) * 4;
        #pragma unroll
        for (int mf = 0; mf < 4; mf++)
            #pragma unroll
            for (int r = 0; r < 4; r++) {
                int row = row0 + mf * 16 + r;
                float bias = qkv_b[1024 + row];
                #pragma unroll
                for (int nf = 0; nf < 4; nf++)
                    out[(size_t)row * 1024 + col0 + nf * 16] = (bf16)(acc[mf][nf][r] + bias);
            }
    }
}

// out[b][o][i] = sum_c wproj[o][c]*attnT[b][i][c] + proj_b[o] + x[b][o][i]
// XBF: residual read from 16MB bf16 shadow instead of 64MB fp32 x.
template <bool XBF>
__global__ __launch_bounds__(256, 2) void gemm_proj(const bf16* __restrict__ wproj,
                                                    const bf16* __restrict__ attnT,
                                                    const float* __restrict__ proj_b,
                                                    const float* __restrict__ x,
                                                    const bf16* __restrict__ xbf,
                                                    float* __restrict__ out) {
    __shared__ char smem[65536];
    int b = blockIdx.z;
    int wave = threadIdx.x >> 6, lane = threadIdx.x & 63;
    int m_blk = blockIdx.x * 128;            // o
    int n_blk = blockIdx.y * 128;            // i
    const bf16* Bm = attnT + (size_t)b * 1024 * 512;
    GEMM_LDS_LOOP(wproj, Bm, smem)
    const float* xb = x + (size_t)b * 512 * 1024;
    const bf16* xbb = xbf + (size_t)b * 512 * 1024;
    float* ob = out + (size_t)b * 512 * 1024;
    int l15 = lane & 15;
    int col0 = n_blk + (wave & 1) * 64 + l15;
    int row0 = m_blk + (wave >> 1) * 64 + (lane >> 4) * 4;
    #pragma unroll
    for (int mf = 0; mf < 4; mf++)
        #pragma unroll
        for (int r = 0; r < 4; r++) {
            int row = row0 + mf * 16 + r;
            float bias = proj_b[row];
            #pragma unroll
            for (int nf = 0; nf < 4; nf++) {
                size_t idx = (size_t)row * 1024 + col0 + nf * 16;
                float res = XBF ? (float)xbb[idx] : xb[idx];
                ob[idx] = acc[mf][nf][r] + bias + res;
            }
        }
}

// ---------------- flash attention, 32x32 MFMA, 2-wave blocks ----------------
// Grid: 2048 blocks flat = [it 16][bh 128]; XCD-bijective (flat%8 = bh%8).
// 2 waves/block, 32 queries/wave (64 q/block). Same r10 schedule + compute body;
// ONLY the barrier-group size changes: 2-wave groups double the number of
// independently-schedulable groups per CU (rounds 7-21: all levers that kept
// one 4-wave group were null -- group independence is the last untested axis).
// Each wave stages 4 K-segs + 4 V-segs (interleaved, segs w,w+2,w+4,w+6);
// counted vmcnt(8) = own previous-tile loads. LDS 32KB/block (unchanged).
__global__ __launch_bounds__(128, 2) void attn_kernel(const bf16* __restrict__ qk_t,
                                                      const bf16* __restrict__ vbuf,
                                                      bf16* __restrict__ attnT) {
    int flat = blockIdx.x;
    int it = flat >> 7;          // 0..15 (64-query tiles)
    int bh = flat & 127;
    int b = bh >> 3, h = bh & 7;
    int wave = threadIdx.x >> 6, lane = threadIdx.x & 63;
    int l31 = lane & 31, hi = lane >> 5;
    int i0 = it * 64 + wave * 32;
    const bf16* qkb = qk_t + (size_t)b * 1024 * 1024;
    const bf16* kbase = qkb + 512 + h * 64;                      // K rows (j), stride 1024
    const bf16* vb = vbuf + ((size_t)b * 512 + h * 64) * 1024;   // V rows (d), stride 1024

    __shared__ __align__(16) char smem[32768];  // 2 bufs x (K 8KB + V 8KB); reused for O^T

    // Q as B-operand: col=q=l31, k = 16kc + 8hi + e
    bf16x8 bq[4];
    #pragma unroll
    for (int kc = 0; kc < 4; kc++)
        bq[kc] = ld8(qkb + (size_t)(i0 + l31) * 1024 + h * 64 + kc * 16 + hi * 8);

    f32x16 oacc[2] = {};
    f32x4 l4 = {};

    // ---- hoisted stage addressing: wave w stages segs {w,w+2,w+4,w+6} (K and V) ----
    int srow = wave * 8 + (lane >> 3);              // rows w*8..w*8+7 (+16k per load)
    int cg = (lane & 7) ^ (lane >> 3);              // pre-swizzled source chunk
    const char* kp = (const char*)kbase + (size_t)srow * 2048 + cg * 16;
    const char* vp = (const char*)vb + (size_t)srow * 2048 + cg * 16;
    char* ldsW = smem + wave * 1024;                // + j*2048 (+8192 for V) + buf*16384

#define ATTN_STAGE(BUFI)                                      \
    {                                                         \
        char* Kb = ldsW + (BUFI) * 16384;                     \
        gl_lds16(kp,          Kb);                            \
        gl_lds16(kp + 32768,  Kb + 2048);                     \
        gl_lds16(kp + 65536,  Kb + 4096);                     \
        gl_lds16(kp + 98304,  Kb + 6144);                     \
        gl_lds16(vp,          Kb + 8192);                     \
        gl_lds16(vp + 32768,  Kb + 10240);                    \
        gl_lds16(vp + 65536,  Kb + 12288);                    \
        gl_lds16(vp + 98304,  Kb + 14336);                    \
        kp += 131072;                                         \
        vp += 128;                                            \
    }

    // ---- hoisted compute read addressing: 4 per-lane vaddrs, rest immediates ----
    int rx = l31 & 7;
    int vaddr[4];
    #pragma unroll
    for (int k = 0; k < 4; k++) vaddr[k] = l31 * 128 + (((k * 2 + hi) ^ rx) * 16);

#define ATTN_COMPUTE(BUFC)                                                              \
    {                                                                                   \
        bf16x8 kf[2][4];                                                                \
        _Pragma("unroll")                                                               \
        for (int jb = 0; jb < 2; jb++)                                                  \
            _Pragma("unroll")                                                           \
            for (int kc = 0; kc < 4; kc++)                                              \
                kf[jb][kc] = *reinterpret_cast<const bf16x8*>(                          \
                    smem + (BUFC) * 16384 + jb * 4096 + vaddr[kc]);                     \
        f32x16 s[2] = {};                                                               \
        _Pragma("unroll")                                                               \
        for (int kc = 0; kc < 4; kc++) {                                                \
            s[0] = __builtin_amdgcn_mfma_f32_32x32x16_bf16(kf[0][kc], bq[kc], s[0], 0, 0, 0); \
            s[1] = __builtin_amdgcn_mfma_f32_32x32x16_bf16(kf[1][kc], bq[kc], s[1], 0, 0, 0); \
        }                                                                               \
        bf16x8 vf[2][4];                                                                \
        _Pragma("unroll")                                                               \
        for (int df = 0; df < 2; df++)                                                  \
            _Pragma("unroll")                                                           \
            for (int ks = 0; ks < 4; ks++)                                              \
                vf[df][ks] = *reinterpret_cast<const bf16x8*>(                          \
                    smem + (BUFC) * 16384 + 8192 + df * 4096 + vaddr[ks]);              \
        unsigned int pk0[2][4], pk1[2][4];                                              \
        _Pragma("unroll")                                                               \
        for (int jb = 0; jb < 2; jb++)                                                  \
            _Pragma("unroll")                                                           \
            for (int m = 0; m < 4; m++) {                                               \
                float e0 = exp2f(s[jb][m * 4 + 0]);                                     \
                float e1 = exp2f(s[jb][m * 4 + 1]);                                     \
                float e2 = exp2f(s[jb][m * 4 + 2]);                                     \
                float e3 = exp2f(s[jb][m * 4 + 3]);                                     \
                f32x4 ev = {e0, e1, e2, e3};                                            \
                l4 += ev;                                                               \
                asm("v_cvt_pk_bf16_f32 %0, %1, %2" : "=v"(pk0[jb][m]) : "v"(e0), "v"(e1)); \
                asm("v_cvt_pk_bf16_f32 %0, %1, %2" : "=v"(pk1[jb][m]) : "v"(e2), "v"(e3)); \
            }                                                                           \
        bf16x8 af[4];                                                                   \
        _Pragma("unroll")                                                               \
        for (int jb = 0; jb < 2; jb++)                                                  \
            _Pragma("unroll")                                                           \
            for (int tt = 0; tt < 2; tt++) {                                            \
                unsigned int a0 = pk0[jb][tt * 2], b0 = pk0[jb][tt * 2 + 1];            \
                unsigned int a1 = pk1[jb][tt * 2], b1 = pk1[jb][tt * 2 + 1];            \
                asm("v_permlane32_swap_b32 %0, %1" : "+v"(a0), "+v"(b0));               \
                asm("v_permlane32_swap_b32 %0, %1" : "+v"(a1), "+v"(b1));               \
                u32x4 w = {a0, a1, b0, b1};                                             \
                af[jb * 2 + tt] = __builtin_bit_cast(bf16x8, w);                        \
            }                                                                           \
        _Pragma("unroll")                                                               \
        for (int ks = 0; ks < 4; ks++) {                                                \
            oacc[0] = __builtin_amdgcn_mfma_f32_32x32x16_bf16(af[ks], vf[0][ks], oacc[0], 0, 0, 0); \
            oacc[1] = __builtin_amdgcn_mfma_f32_32x32x16_bf16(af[ks], vf[1][ks], oacc[1], 0, 0, 0); \
        }                                                                               \
    }

    ATTN_STAGE(0)                    // tile 0 -> buf 0 (8 loads in flight)

    for (int t = 0; t < 16; t += 2) {
        // ---- sub-iter A: compute buf0 (tile t), stage tile t+1 -> buf1 ----
        asm volatile("" ::: "memory");
        __builtin_amdgcn_s_barrier();            // done reading buf1's old contents
        ATTN_STAGE(1)                            // +8 loads
        asm volatile("s_waitcnt vmcnt(8)" ::: "memory");  // tile t landed
        __builtin_amdgcn_s_barrier();
        asm volatile("" ::: "memory");
        ATTN_COMPUTE(0)

        // ---- sub-iter B: compute buf1 (tile t+1), stage tile t+2 -> buf0 ----
        asm volatile("" ::: "memory");
        __builtin_amdgcn_s_barrier();
        if (t < 14) {
            ATTN_STAGE(0)
            asm volatile("s_waitcnt vmcnt(8)" ::: "memory");
        } else {
            asm volatile("s_waitcnt vmcnt(0)" ::: "memory");
        }
        __builtin_amdgcn_s_barrier();
        asm volatile("" ::: "memory");
        ATTN_COMPUTE(1)
    }
#undef ATTN_STAGE
#undef ATTN_COMPUTE

    // ---- softmax denominator (lane (0,q)+(1,q) cover all j for query q) ----
    float l_part = (l4[0] + l4[1]) + (l4[2] + l4[3]);
    float lsum = l_part + __shfl_xor(l_part, 32);
    float inv = 1.f / lsum;

    __syncthreads();   // all waves done with K/V LDS before O^T reuse

    // ---- O^T via LDS transpose for coalesced stores (64 rows x 72 elems) ----
    bf16* O_l = (bf16*)smem;
    #pragma unroll
    for (int reg = 0; reg < 16; reg++) {
        int qrow = (reg & 3) + 8 * (reg >> 2) + 4 * hi;
        float iv = __shfl(inv, qrow);   // inv for query qrow (lives in lane qrow)
        O_l[(wave * 32 + qrow) * 72 + l31]      = (bf16)(oacc[0][reg] * iv);
        O_l[(wave * 32 + qrow) * 72 + 32 + l31] = (bf16)(oacc[1][reg] * iv);
    }
    __syncthreads();
    {
        int tt = threadIdx.x;               // 128 threads -> 64 rows x 2 halves
        int il = tt >> 1, half = tt & 1;
        const bf16* lsrc = O_l + il * 72 + half * 32;
        bf16* gdst = attnT + ((size_t)b * 1024 + it * 64 + il) * 512 + h * 64 + half * 32;
        #pragma unroll
        for (int k = 0; k < 4; k++)
            *reinterpret_cast<bf16x8*>(gdst + k * 8) =
                *reinterpret_cast<const bf16x8*>(lsrc + k * 8);
    }
}

extern "C" void kernel_launch(void* const* d_in, const int* in_sizes, int n_in,
                              void* d_out, int out_size, void* d_ws, size_t ws_size,
                              hipStream_t stream) {
    (void)in_sizes; (void)n_in; (void)out_size;
    const float* x      = (const float*)d_in[0];
    const float* norm_w = (const float*)d_in[1];
    const float* norm_b = (const float*)d_in[2];
    const float* qkv_w  = (const float*)d_in[3];
    const float* qkv_b  = (const float*)d_in[4];
    const float* proj_w = (const float*)d_in[5];
    const float* proj_b = (const float*)d_in[6];
    float* out = (float*)d_out;

    // workspace layout (82 MB base + optional 16 MB xbf)
    char* w = (char*)d_ws;
    bf16* wqkv  = (bf16*)w;                        // 1536*512
    bf16* wproj = wqkv + (size_t)1536 * 512;       // 512*512 (contiguous after wqkv)
    bf16* hnT   = wproj + (size_t)512 * 512;       // [16][1024][512]
    bf16* qk_t  = hnT + (size_t)16 * 1024 * 512;   // [16][1024][1024]
    bf16* vbuf  = qk_t + (size_t)16 * 1024 * 1024; // [16][512][1024]
    bf16* attnT = vbuf + (size_t)16 * 512 * 1024;  // [16][1024][512]
    bf16* xbf_cand = attnT + (size_t)16 * 1024 * 512;
    const size_t need = ((char*)(xbf_cand + (size_t)16 * 512 * 1024)) - w;
    bf16* xbf = (ws_size >= need) ? xbf_cand : nullptr;   // deterministic per-env

    const int GN_LDS = 131072 + 64;
    hipFuncSetAttribute((const void*)gn_cvt_onepass,
                        hipFuncAttributeMaxDynamicSharedMemorySize, GN_LDS);
    gn_cvt_onepass<<<128, 256, GN_LDS, stream>>>(x, norm_w, norm_b, hnT,
                                                 qkv_w, proj_w, wqkv, xbf);
    gemm_qkv<<<dim3(8, 12, 16), 256, 0, stream>>>(hnT, wqkv, qkv_b, qk_t, vbuf);
    attn_kernel<<<2048, 128, 0, stream>>>(qk_t, vbuf, attnT);
    if (xbf)
        gemm_proj<true><<<dim3(4, 8, 16), 256, 0, stream>>>(wproj, attnT, proj_b,
                                                            x, xbf, out);
    else
        gemm_proj<false><<<dim3(4, 8, 16), 256, 0, stream>>>(wproj, attnT, proj_b,
                                                             x, nullptr, out);
}

// Round 23
// 119.424 us; speedup vs baseline: 1.1334x; 1.1334x over previous
//
#include <hip/hip_runtime.h>
#include <hip/hip_bf16.h>

// AttentionBlock: groupnorm -> qkv conv1x1 -> MHA (8 heads, hd=64) -> proj -> residual
// B=16, C=512, H=W=32 (HW=1024). All GEMM-shaped work in bf16 MFMA, fp32 accum.

typedef __bf16 bf16;
typedef __attribute__((ext_vector_type(8))) __bf16 bf16x8;
typedef __attribute__((ext_vector_type(4))) float f32x4;
typedef __attribute__((ext_vector_type(16))) float f32x16;
typedef __attribute__((ext_vector_type(4))) unsigned int u32x4;

#define SCALE_Q 0.18033688f  // 0.125 * log2(e), folded into q at gemm epilogue

__device__ __forceinline__ bf16x8 ld8(const bf16* p) {
    return *reinterpret_cast<const bf16x8*>(p);
}

__device__ __forceinline__ void gl_lds16(const void* g, void* l) {
    __builtin_amdgcn_global_load_lds(
        (const __attribute__((address_space(1))) void*)g,
        (__attribute__((address_space(3))) void*)l, 16, 0, 0);
}

// ---------------- one-pass groupnorm + weight cvt, 128 blocks ----------------
__global__ __launch_bounds__(256) void gn_cvt_onepass(const float* __restrict__ x,
                                                      const float* __restrict__ gamma,
                                                      const float* __restrict__ beta,
                                                      bf16* __restrict__ hnT,
                                                      const float* __restrict__ qkv_w,
                                                      const float* __restrict__ proj_w,
                                                      bf16* __restrict__ wdst,
                                                      bf16* __restrict__ xbf) {
    extern __shared__ char dsm[];            // 131072B cache + 64B reduce scratch
    bf16* xc = (bf16*)dsm;                   // [64 c][128 chunks][8 p] swizzled
    float* red = (float*)(dsm + 131072);
    int bg = blockIdx.x;
    int b = bg >> 3, g = bg & 7;
    const float* base = x + (size_t)bg * 65536;
    int t = threadIdx.x, wave = t >> 6, lane = t & 63;

    // ---- weight cvt chunk: 8192 elems/block (blocks 0..95 qkv, 96..127 proj) ----
    {
        const float* src = (bg < 96) ? qkv_w + bg * 8192 : proj_w + (bg - 96) * 8192;
        bf16* dst = wdst + (size_t)bg * 8192;
        #pragma unroll
        for (int k = 0; k < 8; k++) {
            int i = k * 1024 + t * 4;
            float4 f = *reinterpret_cast<const float4*>(src + i);
            dst[i + 0] = (bf16)f.x;
            dst[i + 1] = (bf16)f.y;
            dst[i + 2] = (bf16)f.z;
            dst[i + 3] = (bf16)f.w;
        }
    }

    // ---- pass 1: stream x, accumulate stats, cache bf16 in LDS ----
    float s = 0.f, sq = 0.f;
    int pc = t >> 1, half = t & 1;
    {
        for (int k = 0; k < 64; k++) {
            float4 f = *reinterpret_cast<const float4*>(base + (size_t)k * 1024 + t * 4);
            s += (f.x + f.y) + (f.z + f.w);
            sq += (f.x * f.x + f.y * f.y) + (f.z * f.z + f.w * f.w);
            unsigned pk0, pk1;
            asm("v_cvt_pk_bf16_f32 %0, %1, %2" : "=v"(pk0) : "v"(f.x), "v"(f.y));
            asm("v_cvt_pk_bf16_f32 %0, %1, %2" : "=v"(pk1) : "v"(f.z), "v"(f.w));
            char* dst = (char*)xc + k * 2048 + ((pc ^ (k & 7)) * 16) + half * 8;
            *reinterpret_cast<uint2*>(dst) = make_uint2(pk0, pk1);
        }
    }
    #pragma unroll
    for (int off = 32; off > 0; off >>= 1) {
        s += __shfl_down(s, off);
        sq += __shfl_down(sq, off);
    }
    if (lane == 0) { red[wave] = s; red[4 + wave] = sq; }
    __syncthreads();
    if (t == 0) {
        float S = (red[0] + red[1]) + (red[2] + red[3]);
        float Q = (red[4] + red[5]) + (red[6] + red[7]);
        float mean = S * (1.f / 65536.f);
        float var = Q * (1.f / 65536.f) - mean * mean;
        red[8] = mean;
        red[9] = rsqrtf(var + 1e-5f);
    }
    __syncthreads();
    float mean = red[8], rstd = red[9];

    // ---- xbf dump: read back own LDS lines, fire-and-forget stores ----
    if (xbf) {
        bf16* xo = xbf + (size_t)bg * 65536;
        for (int k = 0; k < 64; k++) {
            const char* src = (const char*)xc + k * 2048 + ((pc ^ (k & 7)) * 16) + half * 8;
            uint2 v = *reinterpret_cast<const uint2*>(src);
            *reinterpret_cast<uint2*>(xo + (size_t)k * 1024 + t * 4) = v;
        }
    }

    // ---- pass 2: normalize + transpose from LDS cache ----
    int cl = t & 63, quad = t >> 6;
    float ga = gamma[g * 64 + cl] * rstd;
    float be = beta[g * 64 + cl] - mean * ga;
    const char* rowbase = (const char*)xc + cl * 2048;
    int rx = cl & 7;
    bf16* obase = hnT + (size_t)b * 1024 * 512 + g * 64 + cl;
    #pragma unroll 4
    for (int j = 0; j < 32; j++) {
        int pcj = quad + 4 * j;                      // chunk 0..127
        bf16x8 v = *reinterpret_cast<const bf16x8*>(rowbase + ((pcj ^ rx) * 16));
        bf16* ob = obase + (size_t)(pcj * 8) * 512;
        #pragma unroll
        for (int e = 0; e < 8; e++)
            ob[(size_t)e * 512] = (bf16)((float)v[e] * ga + be);
    }
}

// ---------------- staged NT-GEMM core (m97 structure + counted-vmcnt loop) ----------------
__device__ __forceinline__ void gemm_stage(const bf16* __restrict__ A,
                                           const bf16* __restrict__ B,
                                           char* smem, int buf,
                                           int m_blk, int n_blk, int k0,
                                           int wave, int lane) {
    char* Al = smem + buf * 32768;
    char* Bl = Al + 16384;
    #pragma unroll
    for (int i = 0; i < 4; i++) {
        int seg = i * 4 + wave;              // 16 segs of 1KB per 16KB tile
        int r = seg * 8 + (lane >> 3);       // tile row this lane fills
        int cg = (lane & 7) ^ (r & 7);       // pre-swizzled source chunk
        gl_lds16((const char*)(A + (size_t)(m_blk + r) * 512 + k0) + cg * 16,
                 Al + seg * 1024);
        gl_lds16((const char*)(B + (size_t)(n_blk + r) * 512 + k0) + cg * 16,
                 Bl + seg * 1024);
    }
}

__device__ __forceinline__ void gemm_compute(const char* smem, int buf,
                                             int wave, int lane,
                                             f32x4 (&acc)[4][4]) {
    const char* Al = smem + buf * 32768;
    const char* Bl = Al + 16384;
    int l15 = lane & 15, hi = lane >> 4;
    int mb = (wave >> 1) * 64, nb = (wave & 1) * 64;
    #pragma unroll
    for (int kc = 0; kc < 2; kc++) {
        int ck = kc * 4 + hi;                // 16B chunk of the 64-wide k-slab
        bf16x8 a[4], b[4];
        #pragma unroll
        for (int mf = 0; mf < 4; mf++) {
            int row = mb + mf * 16 + l15;
            a[mf] = *reinterpret_cast<const bf16x8*>(Al + row * 128 + (ck ^ (row & 7)) * 16);
        }
        #pragma unroll
        for (int nf = 0; nf < 4; nf++) {
            int row = nb + nf * 16 + l15;
            b[nf] = *reinterpret_cast<const bf16x8*>(Bl + row * 128 + (ck ^ (row & 7)) * 16);
        }
        #pragma unroll
        for (int mf = 0; mf < 4; mf++)
            #pragma unroll
            for (int nf = 0; nf < 4; nf++)
                acc[mf][nf] = __builtin_amdgcn_mfma_f32_16x16x32_bf16(
                    a[mf], b[nf], acc[mf][nf], 0, 0, 0);
    }
}

// Counted-vmcnt double-barrier K-loop (r21, verified): each wave waits only its
// own previous stage (8 loads) so next-tile DMA stays in flight across barriers.
#define GEMM_LDS_LOOP(A_, B_, SMEM_)                                           \
    f32x4 acc[4][4] = {};                                                      \
    {                                                                          \
        gemm_stage(A_, B_, SMEM_, 0, m_blk, n_blk, 0, wave, lane);             \
        for (int ks = 0; ks < 8; ks++) {                                       \
            asm volatile("" ::: "memory");                                     \
            __builtin_amdgcn_s_barrier();                                      \
            if (ks < 7) {                                                      \
                gemm_stage(A_, B_, SMEM_, (ks + 1) & 1, m_blk, n_blk,          \
                           (ks + 1) * 64, wave, lane);                         \
                asm volatile("s_waitcnt vmcnt(8)" ::: "memory");               \
            } else {                                                           \
                asm volatile("s_waitcnt vmcnt(0)" ::: "memory");               \
            }                                                                  \
            __builtin_amdgcn_s_barrier();                                      \
            asm volatile("" ::: "memory");                                     \
            gemm_compute(SMEM_, ks & 1, wave, lane, acc);                      \
        }                                                                      \
    }

// Fused QKV GEMM, one launch. y<8: qk path; y>=8: v path.
__global__ __launch_bounds__(256, 2) void gemm_qkv(const bf16* __restrict__ hnT,
                                                   const bf16* __restrict__ wqkv,
                                                   const float* __restrict__ qkv_b,
                                                   bf16* __restrict__ qk_t,
                                                   bf16* __restrict__ vbuf) {
    __shared__ char smem[65536];
    int b = blockIdx.z;
    int wave = threadIdx.x >> 6, lane = threadIdx.x & 63;
    int l15 = lane & 15;
    int y = blockIdx.y;
    if (y < 8) {
        int m_blk = blockIdx.x * 128;        // p
        int n_blk = y * 128;                 // o
        const bf16* A = hnT + (size_t)b * 1024 * 512;
        GEMM_LDS_LOOP(A, wqkv, smem)
        bf16* out = qk_t + (size_t)b * 1024 * 1024;
        int col0 = n_blk + (wave & 1) * 64 + l15;
        int row0 = m_blk + (wave >> 1) * 64 + (lane >> 4) * 4;
        #pragma unroll
        for (int nf = 0; nf < 4; nf++) {
            int col = col0 + nf * 16;
            float bias = qkv_b[col];
            float scl = (col < 512) ? SCALE_Q : 1.0f;
            #pragma unroll
            for (int mf = 0; mf < 4; mf++)
                #pragma unroll
                for (int r = 0; r < 4; r++)
                    out[(size_t)(row0 + mf * 16 + r) * 1024 + col] =
                        (bf16)((acc[mf][nf][r] + bias) * scl);
        }
    } else {
        int m_blk = (y - 8) * 128;           // o
        int n_blk = blockIdx.x * 128;        // p
        const bf16* A = wqkv + (size_t)1024 * 512;   // wv
        const bf16* Bm = hnT + (size_t)b * 1024 * 512;
        GEMM_LDS_LOOP(A, Bm, smem)
        bf16* out = vbuf + (size_t)b * 512 * 1024;
        int col0 = n_blk + (wave & 1) * 64 + l15;
        int row0 = m_blk + (wave >> 1) * 64 + (lane >> 4) * 4;
        #pragma unroll
        for (int mf = 0; mf < 4; mf++)
            #pragma unroll
            for (int r = 0; r < 4; r++) {
                int row = row0 + mf * 16 + r;
                float bias = qkv_b[1024 + row];
                #pragma unroll
                for (int nf = 0; nf < 4; nf++)
                    out[(size_t)row * 1024 + col0 + nf * 16] = (bf16)(acc[mf][nf][r] + bias);
            }
    }
}

// out[b][o][i] = sum_c wproj[o][c]*attnT[b][i][c] + proj_b[o] + x[b][o][i]
// XBF: residual read from 16MB bf16 shadow instead of 64MB fp32 x.
template <bool XBF>
__global__ __launch_bounds__(256, 2) void gemm_proj(const bf16* __restrict__ wproj,
                                                    const bf16* __restrict__ attnT,
                                                    const float* __restrict__ proj_b,
                                                    const float* __restrict__ x,
                                                    const bf16* __restrict__ xbf,
                                                    float* __restrict__ out) {
    __shared__ char smem[65536];
    int b = blockIdx.z;
    int wave = threadIdx.x >> 6, lane = threadIdx.x & 63;
    int m_blk = blockIdx.x * 128;            // o
    int n_blk = blockIdx.y * 128;            // i
    const bf16* Bm = attnT + (size_t)b * 1024 * 512;
    GEMM_LDS_LOOP(wproj, Bm, smem)
    const float* xb = x + (size_t)b * 512 * 1024;
    const bf16* xbb = xbf + (size_t)b * 512 * 1024;
    float* ob = out + (size_t)b * 512 * 1024;
    int l15 = lane & 15;
    int col0 = n_blk + (wave & 1) * 64 + l15;
    int row0 = m_blk + (wave >> 1) * 64 + (lane >> 4) * 4;
    #pragma unroll
    for (int mf = 0; mf < 4; mf++)
        #pragma unroll
        for (int r = 0; r < 4; r++) {
            int row = row0 + mf * 16 + r;
            float bias = proj_b[row];
            #pragma unroll
            for (int nf = 0; nf < 4; nf++) {
                size_t idx = (size_t)row * 1024 + col0 + nf * 16;
                float res = XBF ? (float)xbb[idx] : xb[idx];
                ob[idx] = acc[mf][nf][r] + bias + res;
            }
        }
}

// ---------------- flash attention, 32x32 MFMA, LDS-staged K/V (r10/r19/r21 body) ----------------
// Grid: 1024 blocks flat = [it 8][bh 128]; XCD-bijective (flat%8 = bh%8).
// 4 waves/block, 32 queries/wave. FROZEN: rounds 7-22 tested nine structural
// axes (barrier count, buffer depth, KVBLK, 8-wave, QBLK, launch-bounds,
// setprio, chain split, 2-wave groups) -- all null or regression. 58.8-60.3us.
__global__ __launch_bounds__(256, 2) void attn_kernel(const bf16* __restrict__ qk_t,
                                                      const bf16* __restrict__ vbuf,
                                                      bf16* __restrict__ attnT) {
    int flat = blockIdx.x;
    int it = flat >> 7;          // 0..7 (128-query tiles)
    int bh = flat & 127;
    int b = bh >> 3, h = bh & 7;
    int wave = threadIdx.x >> 6, lane = threadIdx.x & 63;
    int l31 = lane & 31, hi = lane >> 5;
    int i0 = it * 128 + wave * 32;
    const bf16* qkb = qk_t + (size_t)b * 1024 * 1024;
    const bf16* kbase = qkb + 512 + h * 64;                      // K rows (j), stride 1024
    const bf16* vb = vbuf + ((size_t)b * 512 + h * 64) * 1024;   // V rows (d), stride 1024

    __shared__ __align__(16) char smem[32768];  // 2 bufs x (K 8KB + V 8KB); reused for O^T

    // Q as B-operand: col=q=l31, k = 16kc + 8hi + e
    bf16x8 bq[4];
    #pragma unroll
    for (int kc = 0; kc < 4; kc++)
        bq[kc] = ld8(qkb + (size_t)(i0 + l31) * 1024 + h * 64 + kc * 16 + hi * 8);

    f32x16 oacc[2] = {};
    f32x4 l4 = {};

    // ---- hoisted stage addressing (lane-constant except tile advance) ----
    int srow = wave * 8 + (lane >> 3);              // staged row within tile
    int cg = (lane & 7) ^ (lane >> 3);              // pre-swizzled source chunk
    const char* kp = (const char*)kbase + (size_t)srow * 2048 + cg * 16;
    const char* vp = (const char*)vb + (size_t)srow * 2048 + cg * 16;
    char* ldsK = smem + wave * 1024;                // + i*4096 (+8192 for V) + buf*16384

#define ATTN_STAGE(BUFI)                                     \
    {                                                        \
        gl_lds16(kp,         ldsK + (BUFI) * 16384);         \
        gl_lds16(kp + 65536, ldsK + (BUFI) * 16384 + 4096);  \
        gl_lds16(vp,         ldsK + (BUFI) * 16384 + 8192);  \
        gl_lds16(vp + 65536, ldsK + (BUFI) * 16384 + 12288); \
        kp += 131072;                                        \
        vp += 128;                                           \
    }

    // ---- hoisted compute read addressing: 4 per-lane vaddrs, rest immediates ----
    int rx = l31 & 7;
    int vaddr[4];
    #pragma unroll
    for (int k = 0; k < 4; k++) vaddr[k] = l31 * 128 + (((k * 2 + hi) ^ rx) * 16);

#define ATTN_COMPUTE(BUFC)                                                              \
    {                                                                                   \
        bf16x8 kf[2][4];                                                                \
        _Pragma("unroll")                                                               \
        for (int jb = 0; jb < 2; jb++)                                                  \
            _Pragma("unroll")                                                           \
            for (int kc = 0; kc < 4; kc++)                                              \
                kf[jb][kc] = *reinterpret_cast<const bf16x8*>(                          \
                    smem + (BUFC) * 16384 + jb * 4096 + vaddr[kc]);                     \
        f32x16 s[2] = {};                                                               \
        _Pragma("unroll")                                                               \
        for (int kc = 0; kc < 4; kc++) {                                                \
            s[0] = __builtin_amdgcn_mfma_f32_32x32x16_bf16(kf[0][kc], bq[kc], s[0], 0, 0, 0); \
            s[1] = __builtin_amdgcn_mfma_f32_32x32x16_bf16(kf[1][kc], bq[kc], s[1], 0, 0, 0); \
        }                                                                               \
        bf16x8 vf[2][4];                                                                \
        _Pragma("unroll")                                                               \
        for (int df = 0; df < 2; df++)                                                  \
            _Pragma("unroll")                                                           \
            for (int ks = 0; ks < 4; ks++)                                              \
                vf[df][ks] = *reinterpret_cast<const bf16x8*>(                          \
                    smem + (BUFC) * 16384 + 8192 + df * 4096 + vaddr[ks]);              \
        unsigned int pk0[2][4], pk1[2][4];                                              \
        _Pragma("unroll")                                                               \
        for (int jb = 0; jb < 2; jb++)                                                  \
            _Pragma("unroll")                                                           \
            for (int m = 0; m < 4; m++) {                                               \
                float e0 = exp2f(s[jb][m * 4 + 0]);                                     \
                float e1 = exp2f(s[jb][m * 4 + 1]);                                     \
                float e2 = exp2f(s[jb][m * 4 + 2]);                                     \
                float e3 = exp2f(s[jb][m * 4 + 3]);                                     \
                f32x4 ev = {e0, e1, e2, e3};                                            \
                l4 += ev;                                                               \
                asm("v_cvt_pk_bf16_f32 %0, %1, %2" : "=v"(pk0[jb][m]) : "v"(e0), "v"(e1)); \
                asm("v_cvt_pk_bf16_f32 %0, %1, %2" : "=v"(pk1[jb][m]) : "v"(e2), "v"(e3)); \
            }                                                                           \
        bf16x8 af[4];                                                                   \
        _Pragma("unroll")                                                               \
        for (int jb = 0; jb < 2; jb++)                                                  \
            _Pragma("unroll")                                                           \
            for (int tt = 0; tt < 2; tt++) {                                            \
                unsigned int a0 = pk0[jb][tt * 2], b0 = pk0[jb][tt * 2 + 1];            \
                unsigned int a1 = pk1[jb][tt * 2], b1 = pk1[jb][tt * 2 + 1];            \
                asm("v_permlane32_swap_b32 %0, %1" : "+v"(a0), "+v"(b0));               \
                asm("v_permlane32_swap_b32 %0, %1" : "+v"(a1), "+v"(b1));               \
                u32x4 w = {a0, a1, b0, b1};                                             \
                af[jb * 2 + tt] = __builtin_bit_cast(bf16x8, w);                        \
            }                                                                           \
        _Pragma("unroll")                                                               \
        for (int ks = 0; ks < 4; ks++) {                                                \
            oacc[0] = __builtin_amdgcn_mfma_f32_32x32x16_bf16(af[ks], vf[0][ks], oacc[0], 0, 0, 0); \
            oacc[1] = __builtin_amdgcn_mfma_f32_32x32x16_bf16(af[ks], vf[1][ks], oacc[1], 0, 0, 0); \
        }                                                                               \
    }

    ATTN_STAGE(0)                    // tile 0 -> buf 0 (4 loads in flight)

    for (int t = 0; t < 16; t += 2) {
        // ---- sub-iter A: compute buf0 (tile t), stage tile t+1 -> buf1 ----
        asm volatile("" ::: "memory");
        __builtin_amdgcn_s_barrier();            // done reading buf1's old contents
        ATTN_STAGE(1)                            // +4 loads
        asm volatile("s_waitcnt vmcnt(4)" ::: "memory");  // tile t landed
        __builtin_amdgcn_s_barrier();
        asm volatile("" ::: "memory");
        ATTN_COMPUTE(0)

        // ---- sub-iter B: compute buf1 (tile t+1), stage tile t+2 -> buf0 ----
        asm volatile("" ::: "memory");
        __builtin_amdgcn_s_barrier();
        if (t < 14) {
            ATTN_STAGE(0)
            asm volatile("s_waitcnt vmcnt(4)" ::: "memory");
        } else {
            asm volatile("s_waitcnt vmcnt(0)" ::: "memory");
        }
        __builtin_amdgcn_s_barrier();
        asm volatile("" ::: "memory");
        ATTN_COMPUTE(1)
    }
#undef ATTN_STAGE
#undef ATTN_COMPUTE

    // ---- softmax denominator (lane (0,q)+(1,q) cover all j for query q) ----
    float l_part = (l4[0] + l4[1]) + (l4[2] + l4[3]);
    float lsum = l_part + __shfl_xor(l_part, 32);
    float inv = 1.f / lsum;

    __syncthreads();   // all waves done with K/V LDS before O^T reuse

    // ---- O^T via LDS transpose for coalesced stores ----
    bf16* O_l = (bf16*)smem;
    #pragma unroll
    for (int reg = 0; reg < 16; reg++) {
        int qrow = (reg & 3) + 8 * (reg >> 2) + 4 * hi;
        float iv = __shfl(inv, qrow);   // inv for query qrow (lives in lane qrow)
        O_l[(wave * 32 + qrow) * 72 + l31]      = (bf16)(oacc[0][reg] * iv);
        O_l[(wave * 32 + qrow) * 72 + 32 + l31] = (bf16)(oacc[1][reg] * iv);
    }
    __syncthreads();
    {
        int tt = threadIdx.x;
        int il = tt >> 1, half = tt & 1;
        const bf16* lsrc = O_l + il * 72 + half * 32;
        bf16* gdst = attnT + ((size_t)b * 1024 + it * 128 + il) * 512 + h * 64 + half * 32;
        #pragma unroll
        for (int k = 0; k < 4; k++)
            *reinterpret_cast<bf16x8*>(gdst + k * 8) =
                *reinterpret_cast<const bf16x8*>(lsrc + k * 8);
    }
}

extern "C" void kernel_launch(void* const* d_in, const int* in_sizes, int n_in,
                              void* d_out, int out_size, void* d_ws, size_t ws_size,
                              hipStream_t stream) {
    (void)in_sizes; (void)n_in; (void)out_size;
    const float* x      = (const float*)d_in[0];
    const float* norm_w = (const float*)d_in[1];
    const float* norm_b = (const float*)d_in[2];
    const float* qkv_w  = (const float*)d_in[3];
    const float* qkv_b  = (const float*)d_in[4];
    const float* proj_w = (const float*)d_in[5];
    const float* proj_b = (const float*)d_in[6];
    float* out = (float*)d_out;

    // workspace layout (82 MB base + optional 16 MB xbf)
    char* w = (char*)d_ws;
    bf16* wqkv  = (bf16*)w;                        // 1536*512
    bf16* wproj = wqkv + (size_t)1536 * 512;       // 512*512 (contiguous after wqkv)
    bf16* hnT   = wproj + (size_t)512 * 512;       // [16][1024][512]
    bf16* qk_t  = hnT + (size_t)16 * 1024 * 512;   // [16][1024][1024]
    bf16* vbuf  = qk_t + (size_t)16 * 1024 * 1024; // [16][512][1024]
    bf16* attnT = vbuf + (size_t)16 * 512 * 1024;  // [16][1024][512]
    bf16* xbf_cand = attnT + (size_t)16 * 1024 * 512;
    const size_t need = ((char*)(xbf_cand + (size_t)16 * 512 * 1024)) - w;
    bf16* xbf = (ws_size >= need) ? xbf_cand : nullptr;   // deterministic per-env

    const int GN_LDS = 131072 + 64;
    hipFuncSetAttribute((const void*)gn_cvt_onepass,
                        hipFuncAttributeMaxDynamicSharedMemorySize, GN_LDS);
    gn_cvt_onepass<<<128, 256, GN_LDS, stream>>>(x, norm_w, norm_b, hnT,
                                                 qkv_w, proj_w, wqkv, xbf);
    gemm_qkv<<<dim3(8, 12, 16), 256, 0, stream>>>(hnT, wqkv, qkv_b, qk_t, vbuf);
    attn_kernel<<<1024, 256, 0, stream>>>(qk_t, vbuf, attnT);
    if (xbf)
        gemm_proj<true><<<dim3(4, 8, 16), 256, 0, stream>>>(wproj, attnT, proj_b,
                                                            x, xbf, out);
    else
        gemm_proj<false><<<dim3(4, 8, 16), 256, 0, stream>>>(wproj, attnT, proj_b,
                                                             x, nullptr, out);
}